// Round 1
// baseline (2830.775 us; speedup 1.0000x reference)
//
#include <hip/hip_runtime.h>
#include <hip/hip_bf16.h>

#define Bsz 4096
#define Dsz 256
#define Hsz 512
#define Tsz 45

typedef __attribute__((ext_vector_type(8))) short short8;
typedef __attribute__((ext_vector_type(4))) float f32x4;
using bf16 = __hip_bfloat16;

__device__ __forceinline__ float sigf(float x)   { return 1.0f / (1.0f + __expf(-x)); }
__device__ __forceinline__ float tanhft(float x) { return 1.0f - 2.0f / (__expf(2.0f * x) + 1.0f); }

__device__ __forceinline__ void gload16(const void* g, void* l) {
    __builtin_amdgcn_global_load_lds((const __attribute__((address_space(1))) void*)g,
                                     (__attribute__((address_space(3))) void*)l, 16, 0, 0);
}

// ---------------------------------------------------------------------------
// Weight convert / transpose (one-shot). Wt layouts are (N, K) bf16 so the
// MFMA B-fragment (8 contiguous K per lane) is a single 16B load.
// ---------------------------------------------------------------------------
__global__ void k_conv(const float* __restrict__ ef,   const float* __restrict__ ctx,
                       const float* __restrict__ Whi,  const float* __restrict__ Wci,
                       const float* __restrict__ Wih0, const float* __restrict__ Whh0,
                       const float* __restrict__ Wih1, const float* __restrict__ Whh1,
                       const float* __restrict__ Wo1,  const float* __restrict__ Wg1,
                       bf16* __restrict__ efb,  bf16* __restrict__ ctxb,
                       bf16* __restrict__ Wit,  bf16* __restrict__ Wt0,
                       bf16* __restrict__ Wt1,  bf16* __restrict__ Wo1t,
                       bf16* __restrict__ Wg1t)
{
    size_t tid = (size_t)blockIdx.x * blockDim.x + threadIdx.x;
    size_t gsz = (size_t)gridDim.x * blockDim.x;
    for (size_t i = tid; i < (size_t)Bsz * Dsz; i += gsz) {
        efb[i]  = __float2bfloat16(ef[i]);
        ctxb[i] = __float2bfloat16(ctx[i]);
    }
    for (size_t i = tid; i < 2048ull * 512; i += gsz) {     // Wt0[n][k] = W_hh0[k][n]
        size_t n = i >> 9, k = i & 511;
        Wt0[i] = __float2bfloat16(Whh0[k * 2048 + n]);
    }
    for (size_t i = tid; i < 2048ull * 1024; i += gsz) {    // Wt1[n][k] = [W_ih1; W_hh1][k][n]
        size_t n = i >> 10, k = i & 1023;
        Wt1[i] = __float2bfloat16(k < 512 ? Wih1[k * 2048 + n] : Whh1[(k - 512) * 2048 + n]);
    }
    for (size_t i = tid; i < 32ull * 512; i += gsz) {       // Wo1t/Wg1t[c][k]
        size_t c = i >> 9, k = i & 511;
        Wo1t[i] = __float2bfloat16(Wo1[k * 32 + c]);
        Wg1t[i] = __float2bfloat16(Wg1[k * 32 + c]);
    }
    for (size_t i = tid; i < 4096ull * 256; i += gsz) {     // Wit[n][k]: [Wh_init;Wc_init;W_ih0[1:]]^T
        size_t n = i >> 8, k = i & 255;
        float v = (n < 1024) ? Whi[k * 1024 + n]
                : (n < 2048) ? Wci[k * 1024 + (n - 1024)]
                             : Wih0[(1 + k) * 2048 + (n - 2048)];
        Wit[i] = __float2bfloat16(v);
    }
}

// ---------------------------------------------------------------------------
// Init GEMM: [h_init | c_init | ctx_gates] = [ef|ef|ctx] @ Wit^T segments.
// M=4096, N=4096 (3 segments), K=256. Direct global->reg fragments (one-shot).
// ---------------------------------------------------------------------------
__global__ void __launch_bounds__(256)
k_init(const bf16* __restrict__ efb, const bf16* __restrict__ ctxb,
       const bf16* __restrict__ Wit,
       const float* __restrict__ bh,  const float* __restrict__ bc,
       const float* __restrict__ bi0, const float* __restrict__ bh0,
       bf16* __restrict__ h0, bf16* __restrict__ h1,
       float* __restrict__ c0, float* __restrict__ c1,
       bf16* __restrict__ ctxg)
{
    const int t = threadIdx.x, lane = t & 63, w = t >> 6;
    const int wr = w >> 1, wc = w & 1;
    const int lq = lane >> 4, ln = lane & 15;
    const int m0 = blockIdx.x * 128, n0 = blockIdx.y * 64;
    const bf16* A = (n0 < 2048) ? efb : ctxb;

    f32x4 zero = {0.f, 0.f, 0.f, 0.f};
    f32x4 acc[4][2];
#pragma unroll
    for (int r = 0; r < 4; ++r)
#pragma unroll
        for (int c = 0; c < 2; ++c) acc[r][c] = zero;

    for (int k0 = 0; k0 < 256; k0 += 32) {
        short8 af[4];
#pragma unroll
        for (int r = 0; r < 4; ++r)
            af[r] = *(const short8*)(A + (size_t)(m0 + wr * 64 + r * 16 + ln) * 256 + k0 + lq * 8);
#pragma unroll
        for (int c = 0; c < 2; ++c) {
            short8 bv = *(const short8*)(Wit + (size_t)(n0 + wc * 32 + c * 16 + ln) * 256 + k0 + lq * 8);
#pragma unroll
            for (int r = 0; r < 4; ++r)
                acc[r][c] = __builtin_amdgcn_mfma_f32_16x16x32_bf16(af[r], bv, acc[r][c], 0, 0, 0);
        }
    }
#pragma unroll
    for (int r = 0; r < 4; ++r)
#pragma unroll
        for (int c = 0; c < 2; ++c)
#pragma unroll
            for (int e = 0; e < 4; ++e) {
                int b = m0 + wr * 64 + r * 16 + lq * 4 + e;
                int n = n0 + wc * 32 + c * 16 + ln;
                float v = acc[r][c][e];
                if (n < 1024) {
                    v += bh[n];
                    if (n < 512) h0[(size_t)b * 512 + n]       = __float2bfloat16(v);
                    else         h1[(size_t)b * 512 + n - 512] = __float2bfloat16(v);
                } else if (n < 2048) {
                    int m = n - 1024; v += bc[m];
                    if (m < 512) c0[(size_t)b * 512 + m]       = v;
                    else         c1[(size_t)b * 512 + m - 512] = v;
                } else {
                    int j = n - 2048;
                    ctxg[(size_t)b * 2048 + j] = __float2bfloat16(v + bi0[j] + bh0[j]);
                }
            }
}

// ---------------------------------------------------------------------------
// Fused gates GEMM + LSTM cell. Each WG owns 128 rows x 32 gate-cols x 4 gates
// (= 128x128 outputs), so i/f/g/o for a (b,j) pair live in one wave and the
// cell fuses into the epilogue. L0=1: K=512 (h0@W_hh0) + ctx + intent rank-1.
// L0=0: K=1024 over [h0n ; h1] with Wt1=[W_ih1;W_hh1]^T.
// ---------------------------------------------------------------------------
template <int L0>
__global__ void __launch_bounds__(256)
k_gates(const bf16* __restrict__ hA, const bf16* __restrict__ hB,
        const bf16* __restrict__ Wt,
        const bf16* __restrict__ ctxg, const float* __restrict__ intent,
        const float* __restrict__ w0row,
        const float* __restrict__ b1, const float* __restrict__ b2,
        float* __restrict__ cbuf, bf16* __restrict__ hout)
{
    constexpr int KW = L0 ? 512 : 1024;
    __shared__ __align__(16) bf16 As[128 * 32];
    __shared__ __align__(16) bf16 Bs[4 * 32 * 32];
    const int t = threadIdx.x;
    const int lane = t & 63, w = t >> 6;
    const int wr = w >> 1, wc = w & 1;
    const int lq = lane >> 4, ln = lane & 15;
    const int m0 = blockIdx.x * 128, j0 = blockIdx.y * 32;

    f32x4 zero = {0.f, 0.f, 0.f, 0.f};
    f32x4 acc[4][4];
#pragma unroll
    for (int g = 0; g < 4; ++g)
#pragma unroll
        for (int r = 0; r < 4; ++r) acc[g][r] = zero;

    for (int k0 = 0; k0 < KW; k0 += 32) {
        __syncthreads();
        // ---- stage A tile [128 rows][32 k] via global_load_lds (16B/lane),
        //      chunk XOR-swizzled: LDS slot (row,kc) holds global chunk kc^((row>>2)&3)
#pragma unroll
        for (int i = 0; i < 2; ++i) {
            int chunk = i * 256 + t;
            int row = chunk >> 2, kc = chunk & 3;
            int kk = k0 + (kc ^ ((row >> 2) & 3)) * 8;
            const bf16* src;
            if (L0) src = hA + (size_t)(m0 + row) * Hsz + kk;
            else    src = (k0 < 512) ? hA + (size_t)(m0 + row) * Hsz + kk
                                     : hB + (size_t)(m0 + row) * Hsz + (kk - 512);
            gload16(src, (char*)As + (size_t)(i * 256 + w * 64) * 16);
        }
        // ---- stage B tiles [4 gates][32 n][32 k] from Wt (N,K): same swizzle on n
#pragma unroll
        for (int i = 0; i < 2; ++i) {
            int chunk = i * 256 + t;
            int g = chunk >> 7, rem = chunk & 127;
            int n = rem >> 2, kc = rem & 3;
            int kk = k0 + (kc ^ ((n >> 2) & 3)) * 8;
            const bf16* src = Wt + (size_t)(g * 512 + j0 + n) * KW + kk;
            gload16(src, (char*)Bs + (size_t)(i * 256 + w * 64) * 16);
        }
        __syncthreads();

        short8 af[4];
#pragma unroll
        for (int r = 0; r < 4; ++r) {
            int row = wr * 64 + r * 16 + ln;
            int c = lq ^ ((row >> 2) & 3);
            af[r] = *(const short8*)(As + row * 32 + c * 8);
        }
#pragma unroll
        for (int g = 0; g < 4; ++g) {
            int n = wc * 16 + ln;
            int c = lq ^ ((n >> 2) & 3);
            short8 bv = *(const short8*)(Bs + (g * 32 + n) * 32 + c * 8);
#pragma unroll
            for (int r = 0; r < 4; ++r)
                acc[g][r] = __builtin_amdgcn_mfma_f32_16x16x32_bf16(af[r], bv, acc[g][r], 0, 0, 0);
        }
    }

    // ---- fused LSTM cell epilogue. C/D frag: col=lane&15, row=(lane>>4)*4+reg
    const int jl = j0 + wc * 16 + ln;
    float addc[4];
#pragma unroll
    for (int g = 0; g < 4; ++g)
        addc[g] = L0 ? w0row[g * 512 + jl] : (b1[g * 512 + jl] + b2[g * 512 + jl]);

#pragma unroll
    for (int r = 0; r < 4; ++r)
#pragma unroll
        for (int e = 0; e < 4; ++e) {
            int b = m0 + wr * 64 + r * 16 + lq * 4 + e;
            float pre[4];
#pragma unroll
            for (int g = 0; g < 4; ++g) pre[g] = acc[g][r][e];
            if (L0) {
                float it = intent[b];
#pragma unroll
                for (int g = 0; g < 4; ++g)
                    pre[g] += __bfloat162float(ctxg[(size_t)b * 2048 + g * 512 + jl]) + it * addc[g];
            } else {
#pragma unroll
                for (int g = 0; g < 4; ++g) pre[g] += addc[g];
            }
            float ig = sigf(pre[0]), fg = sigf(pre[1]);
            float gg = tanhft(pre[2]), og = sigf(pre[3]);
            size_t idx = (size_t)b * Hsz + jl;
            float cn = fg * cbuf[idx] + ig * gg;
            cbuf[idx] = cn;
            hout[idx] = __float2bfloat16(og * tanhft(cn));
        }
}

// ---------------------------------------------------------------------------
// intent head: sigmoid(relu(h @ W1 + b1) @ W2 + b2). MFMA (B x 32, K=512),
// intra-wave shfl reduce over the 32 cols, LDS combine across the 2 wc waves.
// ---------------------------------------------------------------------------
__global__ void __launch_bounds__(256)
k_intent(const bf16* __restrict__ h, const bf16* __restrict__ W1t,
         const float* __restrict__ bias1, const float* __restrict__ W2,
         const float* __restrict__ bias2,
         float* __restrict__ outp, int ostride, float* __restrict__ iws)
{
    const int t = threadIdx.x, lane = t & 63, w = t >> 6;
    const int wr = w >> 1, wc = w & 1;
    const int lq = lane >> 4, ln = lane & 15;
    const int m0 = blockIdx.x * 128;
    __shared__ float part[128][2];

    f32x4 zero = {0.f, 0.f, 0.f, 0.f};
    f32x4 acc[4];
#pragma unroll
    for (int r = 0; r < 4; ++r) acc[r] = zero;

    for (int k0 = 0; k0 < 512; k0 += 32) {
        short8 bv = *(const short8*)(W1t + (size_t)(wc * 16 + ln) * 512 + k0 + lq * 8);
#pragma unroll
        for (int r = 0; r < 4; ++r) {
            short8 av = *(const short8*)(h + (size_t)(m0 + wr * 64 + r * 16 + ln) * 512 + k0 + lq * 8);
            acc[r] = __builtin_amdgcn_mfma_f32_16x16x32_bf16(av, bv, acc[r], 0, 0, 0);
        }
    }
    int col = wc * 16 + ln;
    float b1v = bias1[col], w2v = W2[col];
#pragma unroll
    for (int r = 0; r < 4; ++r)
#pragma unroll
        for (int e = 0; e < 4; ++e) {
            float v = fmaxf(acc[r][e] + b1v, 0.f) * w2v;
            v += __shfl_xor(v, 1);
            v += __shfl_xor(v, 2);
            v += __shfl_xor(v, 4);
            v += __shfl_xor(v, 8);
            if (ln == 0) part[wr * 64 + r * 16 + lq * 4 + e][wc] = v;
        }
    __syncthreads();
    if (t < 128) {
        int b = m0 + t;
        float p = sigf(part[t][0] + part[t][1] + bias2[0]);
        outp[(size_t)b * ostride] = p;
        if (iws) iws[b] = p;
    }
}

// ---------------------------------------------------------------------------
extern "C" void kernel_launch(void* const* d_in, const int* in_sizes, int n_in,
                              void* d_out, int out_size, void* d_ws, size_t ws_size,
                              hipStream_t stream)
{
    const float* ef   = (const float*)d_in[0];
    const float* ctx  = (const float*)d_in[1];
    const float* ii   = (const float*)d_in[2];
    const float* Whi  = (const float*)d_in[3];
    const float* bh   = (const float*)d_in[4];
    const float* Wci  = (const float*)d_in[5];
    const float* bc   = (const float*)d_in[6];
    const float* Wih0 = (const float*)d_in[7];
    const float* Whh0 = (const float*)d_in[8];
    const float* bi0  = (const float*)d_in[9];
    const float* bh0  = (const float*)d_in[10];
    const float* Wih1 = (const float*)d_in[11];
    const float* Whh1 = (const float*)d_in[12];
    const float* bi1  = (const float*)d_in[13];
    const float* bh1  = (const float*)d_in[14];
    const float* Wo1  = (const float*)d_in[15];
    const float* bo1  = (const float*)d_in[16];
    const float* Wo2  = (const float*)d_in[17];
    const float* bo2  = (const float*)d_in[18];
    const float* Wg1  = (const float*)d_in[19];
    const float* bg1  = (const float*)d_in[20];
    const float* Wg2  = (const float*)d_in[21];
    const float* bg2  = (const float*)d_in[22];
    float* out = (float*)d_out;

    char* ws = (char*)d_ws;
    size_t off = 0;
    auto take = [&](size_t bytes) -> char* {
        char* p = ws + off;
        off += (bytes + 255) & ~(size_t)255;
        return p;
    };
    bf16* Wt0    = (bf16*)take(2048ull * 512 * 2);
    bf16* Wt1    = (bf16*)take(2048ull * 1024 * 2);
    bf16* Wo1t   = (bf16*)take(32ull * 512 * 2);
    bf16* Wg1t   = (bf16*)take(32ull * 512 * 2);
    bf16* Wit    = (bf16*)take(4096ull * 256 * 2);
    bf16* efb    = (bf16*)take((size_t)Bsz * Dsz * 2);
    bf16* ctxb   = (bf16*)take((size_t)Bsz * Dsz * 2);
    bf16* h0b[2] = {(bf16*)take((size_t)Bsz * Hsz * 2), (bf16*)take((size_t)Bsz * Hsz * 2)};
    bf16* h1b[2] = {(bf16*)take((size_t)Bsz * Hsz * 2), (bf16*)take((size_t)Bsz * Hsz * 2)};
    float* c0    = (float*)take((size_t)Bsz * Hsz * 4);
    float* c1    = (float*)take((size_t)Bsz * Hsz * 4);
    bf16* ctxg   = (bf16*)take((size_t)Bsz * 2048 * 2);
    float* iws   = (float*)take((size_t)Bsz * 4);
    (void)ws_size; (void)in_sizes; (void)n_in; (void)out_size;

    k_conv<<<2048, 256, 0, stream>>>(ef, ctx, Whi, Wci, Wih0, Whh0, Wih1, Whh1, Wo1, Wg1,
                                     efb, ctxb, Wit, Wt0, Wt1, Wo1t, Wg1t);
    k_init<<<dim3(32, 64), 256, 0, stream>>>(efb, ctxb, Wit, bh, bc, bi0, bh0,
                                             h0b[0], h1b[0], c0, c1, ctxg);
    for (int s = 0; s < Tsz; ++s) {
        int p = s & 1;
        const float* it = (s == 0) ? ii : iws;
        k_gates<1><<<dim3(32, 16), 256, 0, stream>>>(h0b[p], nullptr, Wt0, ctxg, it, Wih0,
                                                     nullptr, nullptr, c0, h0b[1 - p]);
        k_gates<0><<<dim3(32, 16), 256, 0, stream>>>(h0b[1 - p], h1b[p], Wt1, nullptr, nullptr,
                                                     nullptr, bi1, bh1, c1, h1b[1 - p]);
        k_intent<<<32, 256, 0, stream>>>(h1b[1 - p], Wo1t, bo1, Wo2, bo2, out + s, Tsz, iws);
    }
    k_intent<<<32, 256, 0, stream>>>(h1b[1], Wg1t, bg1, Wg2, bg2, out + (size_t)Bsz * Tsz, 1, nullptr);
}

// Round 3
// 2757.338 us; speedup vs baseline: 1.0266x; 1.0266x over previous
//
#include <hip/hip_runtime.h>
#include <hip/hip_bf16.h>

#define Bsz 4096
#define Dsz 256
#define Hsz 512
#define Tsz 45

typedef __attribute__((ext_vector_type(8))) short short8;
typedef __attribute__((ext_vector_type(4))) float f32x4;
typedef __attribute__((ext_vector_type(4))) unsigned short us4;
using bf16 = __hip_bfloat16;

__device__ __forceinline__ float sigf(float x)   { return 1.0f / (1.0f + __expf(-x)); }
__device__ __forceinline__ float tanhft(float x) { return 1.0f - 2.0f / (__expf(2.0f * x) + 1.0f); }
__device__ __forceinline__ float b2f(unsigned short u) { return __uint_as_float((unsigned)u << 16); }

__device__ __forceinline__ void gload16(const void* g, void* l) {
    __builtin_amdgcn_global_load_lds((const __attribute__((address_space(1))) void*)g,
                                     (__attribute__((address_space(3))) void*)l, 16, 0, 0);
}

// ---------------------------------------------------------------------------
// Weight convert / transpose (one-shot).
// ---------------------------------------------------------------------------
__global__ void k_conv(const float* __restrict__ ef,   const float* __restrict__ ctx,
                       const float* __restrict__ Whi,  const float* __restrict__ Wci,
                       const float* __restrict__ Wih0, const float* __restrict__ Whh0,
                       const float* __restrict__ Wih1, const float* __restrict__ Whh1,
                       const float* __restrict__ Wo1,  const float* __restrict__ Wg1,
                       bf16* __restrict__ efb,  bf16* __restrict__ ctxb,
                       bf16* __restrict__ Wit,  bf16* __restrict__ Wt0,
                       bf16* __restrict__ Wt1,  bf16* __restrict__ Wo1t,
                       bf16* __restrict__ Wg1t)
{
    size_t tid = (size_t)blockIdx.x * blockDim.x + threadIdx.x;
    size_t gsz = (size_t)gridDim.x * blockDim.x;
    for (size_t i = tid; i < (size_t)Bsz * Dsz; i += gsz) {
        efb[i]  = __float2bfloat16(ef[i]);
        ctxb[i] = __float2bfloat16(ctx[i]);
    }
    for (size_t i = tid; i < 2048ull * 512; i += gsz) {     // Wt0[n][k] = W_hh0[k][n]
        size_t n = i >> 9, k = i & 511;
        Wt0[i] = __float2bfloat16(Whh0[k * 2048 + n]);
    }
    for (size_t i = tid; i < 2048ull * 1024; i += gsz) {    // Wt1[n][k] = [W_ih1; W_hh1][k][n]
        size_t n = i >> 10, k = i & 1023;
        Wt1[i] = __float2bfloat16(k < 512 ? Wih1[k * 2048 + n] : Whh1[(k - 512) * 2048 + n]);
    }
    for (size_t i = tid; i < 32ull * 512; i += gsz) {       // Wo1t/Wg1t[c][k]
        size_t c = i >> 9, k = i & 511;
        Wo1t[i] = __float2bfloat16(Wo1[k * 32 + c]);
        Wg1t[i] = __float2bfloat16(Wg1[k * 32 + c]);
    }
    for (size_t i = tid; i < 4096ull * 256; i += gsz) {     // Wit[n][k]: [Wh_init;Wc_init;W_ih0[1:]]^T
        size_t n = i >> 8, k = i & 255;
        float v = (n < 1024) ? Whi[k * 1024 + n]
                : (n < 2048) ? Wci[k * 1024 + (n - 1024)]
                             : Wih0[(1 + k) * 2048 + (n - 2048)];
        Wit[i] = __float2bfloat16(v);
    }
}

// ---------------------------------------------------------------------------
// Init GEMM: [h_init | c_init | ctx_gates]. ctx_gates stored [b][j][4 gates].
// ---------------------------------------------------------------------------
__global__ void __launch_bounds__(256)
k_init(const bf16* __restrict__ efb, const bf16* __restrict__ ctxb,
       const bf16* __restrict__ Wit,
       const float* __restrict__ bh,  const float* __restrict__ bc,
       const float* __restrict__ bi0, const float* __restrict__ bh0,
       bf16* __restrict__ h0, bf16* __restrict__ h1,
       float* __restrict__ c0, float* __restrict__ c1,
       bf16* __restrict__ ctxg)
{
    const int t = threadIdx.x, lane = t & 63, w = t >> 6;
    const int wr = w >> 1, wc = w & 1;
    const int lq = lane >> 4, ln = lane & 15;
    const int m0 = blockIdx.x * 128, n0 = blockIdx.y * 64;
    const bf16* A = (n0 < 2048) ? efb : ctxb;

    f32x4 zero = {0.f, 0.f, 0.f, 0.f};
    f32x4 acc[4][2];
#pragma unroll
    for (int r = 0; r < 4; ++r)
#pragma unroll
        for (int c = 0; c < 2; ++c) acc[r][c] = zero;

    for (int k0 = 0; k0 < 256; k0 += 32) {
        short8 af[4];
#pragma unroll
        for (int r = 0; r < 4; ++r)
            af[r] = *(const short8*)(A + (size_t)(m0 + wr * 64 + r * 16 + ln) * 256 + k0 + lq * 8);
#pragma unroll
        for (int c = 0; c < 2; ++c) {
            short8 bv = *(const short8*)(Wit + (size_t)(n0 + wc * 32 + c * 16 + ln) * 256 + k0 + lq * 8);
#pragma unroll
            for (int r = 0; r < 4; ++r)
                acc[r][c] = __builtin_amdgcn_mfma_f32_16x16x32_bf16(af[r], bv, acc[r][c], 0, 0, 0);
        }
    }
#pragma unroll
    for (int r = 0; r < 4; ++r)
#pragma unroll
        for (int c = 0; c < 2; ++c)
#pragma unroll
            for (int e = 0; e < 4; ++e) {
                int b = m0 + wr * 64 + r * 16 + lq * 4 + e;
                int n = n0 + wc * 32 + c * 16 + ln;
                float v = acc[r][c][e];
                if (n < 1024) {
                    v += bh[n];
                    if (n < 512) h0[(size_t)b * 512 + n]       = __float2bfloat16(v);
                    else         h1[(size_t)b * 512 + n - 512] = __float2bfloat16(v);
                } else if (n < 2048) {
                    int m = n - 1024; v += bc[m];
                    if (m < 512) c0[(size_t)b * 512 + m]       = v;
                    else         c1[(size_t)b * 512 + m - 512] = v;
                } else {
                    int j = n - 2048;
                    ctxg[(size_t)b * 2048 + (j & 511) * 4 + (j >> 9)] =
                        __float2bfloat16(v + bi0[j] + bh0[j]);
                }
            }
}

// ---------------------------------------------------------------------------
// intent head for 128 rows at m0 (all 4 waves; wave w: rows w*32..+32).
// ---------------------------------------------------------------------------
__device__ __forceinline__ void intent_head(
    const bf16* __restrict__ h, const bf16* __restrict__ W1t,
    const float* __restrict__ b1, const float* __restrict__ W2, float b2s,
    int m0, float* sitp, float* outp, int ostride)
{
    const int t = threadIdx.x, lane = t & 63, w = t >> 6;
    const int lq = lane >> 4, ln = lane & 15;
    f32x4 zero = {0.f, 0.f, 0.f, 0.f};
    f32x4 acc[2][2];
#pragma unroll
    for (int r = 0; r < 2; ++r)
#pragma unroll
        for (int c = 0; c < 2; ++c) acc[r][c] = zero;

#pragma unroll
    for (int k0 = 0; k0 < 512; k0 += 32) {
        short8 av[2], bv[2];
#pragma unroll
        for (int r = 0; r < 2; ++r)
            av[r] = *(const short8*)(h + (size_t)(m0 + w * 32 + r * 16 + ln) * 512 + k0 + lq * 8);
#pragma unroll
        for (int c = 0; c < 2; ++c)
            bv[c] = *(const short8*)(W1t + (size_t)(c * 16 + ln) * 512 + k0 + lq * 8);
#pragma unroll
        for (int r = 0; r < 2; ++r)
#pragma unroll
            for (int c = 0; c < 2; ++c)
                acc[r][c] = __builtin_amdgcn_mfma_f32_16x16x32_bf16(av[r], bv[c], acc[r][c], 0, 0, 0);
    }
#pragma unroll
    for (int r = 0; r < 2; ++r)
#pragma unroll
        for (int e = 0; e < 4; ++e) {
            float v = 0.f;
#pragma unroll
            for (int c = 0; c < 2; ++c) {
                int col = c * 16 + ln;
                v += fmaxf(acc[r][c][e] + b1[col], 0.f) * W2[col];
            }
            v += __shfl_xor(v, 1);
            v += __shfl_xor(v, 2);
            v += __shfl_xor(v, 4);
            v += __shfl_xor(v, 8);
            int row = w * 32 + r * 16 + lq * 4 + e;
            if (ln == 0) {
                float p = sigf(v + b2s);
                if (sitp) sitp[row] = p;
                if (outp) outp[(size_t)(m0 + row) * ostride] = p;
            }
        }
}

// ---------------------------------------------------------------------------
// Staging: tile (128 rows x 64 K) of A and (4g x 32 n x 64 K) of B into LDS,
// 8-slot XOR swizzle (slot = chunk ^ (row&7)) pre-applied on the GLOBAL side.
// ---------------------------------------------------------------------------
template <int L0>
__device__ __forceinline__ void stage(const bf16* __restrict__ hA, const bf16* __restrict__ hB,
                                      const bf16* __restrict__ Wt,
                                      int m0, int j0, int k0, bf16* Ab, bf16* Bb, int t)
{
    constexpr int KW = L0 ? 512 : 1024;
#pragma unroll
    for (int i = 0; i < 4; ++i) {
        int f = i * 256 + t;
        int row = f >> 3, slot = f & 7;
        int kk = k0 + ((slot ^ (row & 7)) << 3);
        const bf16* src;
        if (L0) src = hA + (size_t)(m0 + row) * Hsz + kk;
        else    src = (kk < 512) ? hA + (size_t)(m0 + row) * Hsz + kk
                                 : hB + (size_t)(m0 + row) * Hsz + (kk - 512);
        gload16(src, (char*)Ab + (size_t)f * 16);
    }
#pragma unroll
    for (int i = 0; i < 4; ++i) {
        int f = i * 256 + t;
        int brow = f >> 3, slot = f & 7;
        int g = brow >> 5, n = brow & 31;
        int kc = slot ^ (brow & 7);
        gload16(Wt + (size_t)(g * 512 + j0 + n) * KW + k0 + kc * 8, (char*)Bb + (size_t)f * 16);
    }
}

// ---------------------------------------------------------------------------
// Fused gates GEMM + LSTM cell (+ intent head for L0). Depth-1 pipelined
// K-loop, BK=64, double-buffered LDS (64 KB), one barrier per K-step.
// Grid: x = jblk (16) so XCD = jblk%8 -> weight slices stay L2-resident.
// ---------------------------------------------------------------------------
template <int L0>
__global__ void __launch_bounds__(256, 2)
k_gates(const bf16* __restrict__ hA, const bf16* __restrict__ hB,
        const bf16* __restrict__ Wt,
        const bf16* __restrict__ ctxg, const float* __restrict__ ii,
        const bf16* __restrict__ h1prev,
        const float* __restrict__ w0row,
        const float* __restrict__ b1, const float* __restrict__ b2,
        const bf16* __restrict__ Wo1t, const float* __restrict__ bo1,
        const float* __restrict__ Wo2, const float* __restrict__ bo2,
        float* __restrict__ cbuf, bf16* __restrict__ hout,
        float* __restrict__ outp, int step)
{
    constexpr int KW = L0 ? 512 : 1024;
    constexpr int NT = KW / 64;
    __shared__ __align__(16) char lds[65536];
    bf16* A0 = (bf16*)lds;
    bf16* A1 = (bf16*)(lds + 16384);
    bf16* B0 = (bf16*)(lds + 32768);
    bf16* B1 = (bf16*)(lds + 49152);
    float* sitp = (float*)(lds + 49152);      // aliases B1 (B1 first written at kt=0)

    const int t = threadIdx.x, lane = t & 63, w = t >> 6;
    const int wr = w >> 1, wc = w & 1, lq = lane >> 4, ln = lane & 15;
    const int j0 = blockIdx.x * 32, m0 = blockIdx.y * 128;

    stage<L0>(hA, hB, Wt, m0, j0, 0, A0, B0, t);    // tile 0 in flight

    float sreg[16];
    if (L0) {
        if (step == 0) {
            if (t < 128) sitp[t] = ii[m0 + t];
        } else {
            intent_head(h1prev, Wo1t, bo1, Wo2, bo2[0], m0, sitp,
                        (blockIdx.x == 0) ? outp + (step - 1) : nullptr, Tsz);
        }
        __syncthreads();                              // sit visible + tile 0 landed
#pragma unroll
        for (int r = 0; r < 4; ++r)
#pragma unroll
            for (int e = 0; e < 4; ++e)
                sreg[r * 4 + e] = sitp[wr * 64 + r * 16 + lq * 4 + e];
        __syncthreads();                              // all read sit before B1 staged
    } else {
        __syncthreads();                              // tile 0 landed
    }

    f32x4 zero = {0.f, 0.f, 0.f, 0.f};
    f32x4 acc[4][4];
#pragma unroll
    for (int g = 0; g < 4; ++g)
#pragma unroll
        for (int r = 0; r < 4; ++r) acc[g][r] = zero;

#pragma unroll 2
    for (int kt = 0; kt < NT; ++kt) {
        if (kt + 1 < NT)
            stage<L0>(hA, hB, Wt, m0, j0, (kt + 1) * 64,
                      (kt & 1) ? A0 : A1, (kt & 1) ? B0 : B1, t);
        const bf16* Ab = (kt & 1) ? A1 : A0;
        const bf16* Bb = (kt & 1) ? B1 : B0;
#pragma unroll
        for (int kk2 = 0; kk2 < 2; ++kk2) {
            short8 af[4], bfr[4];
#pragma unroll
            for (int r = 0; r < 4; ++r) {
                int row = wr * 64 + r * 16 + ln;
                int slot = (kk2 * 4 + lq) ^ (row & 7);
                af[r] = *(const short8*)(Ab + ((size_t)row * 8 + slot) * 8);
            }
#pragma unroll
            for (int g = 0; g < 4; ++g) {
                int brow = g * 32 + wc * 16 + ln;
                int slot = (kk2 * 4 + lq) ^ (brow & 7);
                bfr[g] = *(const short8*)(Bb + ((size_t)brow * 8 + slot) * 8);
            }
#pragma unroll
            for (int g = 0; g < 4; ++g)
#pragma unroll
                for (int r = 0; r < 4; ++r)
                    acc[g][r] = __builtin_amdgcn_mfma_f32_16x16x32_bf16(af[r], bfr[g], acc[g][r], 0, 0, 0);
        }
        if (kt + 1 < NT) __syncthreads();             // tile kt+1 landed; cur fully read
    }

    // ---- fused LSTM cell epilogue. C/D frag: col=lane&15, row=(lane>>4)*4+reg
    const int jl = j0 + wc * 16 + ln;
    float addc[4];
#pragma unroll
    for (int g = 0; g < 4; ++g)
        addc[g] = L0 ? w0row[g * 512 + jl] : (b1[g * 512 + jl] + b2[g * 512 + jl]);

#pragma unroll
    for (int r = 0; r < 4; ++r)
#pragma unroll
        for (int e = 0; e < 4; ++e) {
            int b = m0 + wr * 64 + r * 16 + lq * 4 + e;
            float pre[4];
#pragma unroll
            for (int g = 0; g < 4; ++g) pre[g] = acc[g][r][e];
            if (L0) {
                float it = sreg[r * 4 + e];
                us4 cg = *(const us4*)((const unsigned short*)ctxg + (size_t)b * 2048 + jl * 4);
#pragma unroll
                for (int g = 0; g < 4; ++g) pre[g] += b2f(cg[g]) + it * addc[g];
            } else {
#pragma unroll
                for (int g = 0; g < 4; ++g) pre[g] += addc[g];
            }
            float ig = sigf(pre[0]), fg = sigf(pre[1]);
            float gg = tanhft(pre[2]), og = sigf(pre[3]);
            size_t idx = (size_t)b * Hsz + jl;
            float cn = fg * cbuf[idx] + ig * gg;
            cbuf[idx] = cn;
            hout[idx] = __float2bfloat16(og * tanhft(cn));
        }
}

// ---------------------------------------------------------------------------
// standalone head (final step intent + global head)
// ---------------------------------------------------------------------------
__global__ void __launch_bounds__(256)
k_intent(const bf16* __restrict__ h, const bf16* __restrict__ W1t,
         const float* __restrict__ bias1, const float* __restrict__ W2,
         const float* __restrict__ bias2,
         float* __restrict__ outp, int ostride)
{
    intent_head(h, W1t, bias1, W2, bias2[0], blockIdx.x * 128, nullptr, outp, ostride);
}

// ---------------------------------------------------------------------------
extern "C" void kernel_launch(void* const* d_in, const int* in_sizes, int n_in,
                              void* d_out, int out_size, void* d_ws, size_t ws_size,
                              hipStream_t stream)
{
    const float* ef   = (const float*)d_in[0];
    const float* ctx  = (const float*)d_in[1];
    const float* ii   = (const float*)d_in[2];
    const float* Whi  = (const float*)d_in[3];
    const float* bh   = (const float*)d_in[4];
    const float* Wci  = (const float*)d_in[5];
    const float* bc   = (const float*)d_in[6];
    const float* Wih0 = (const float*)d_in[7];
    const float* Whh0 = (const float*)d_in[8];
    const float* bi0  = (const float*)d_in[9];
    const float* bh0  = (const float*)d_in[10];
    const float* Wih1 = (const float*)d_in[11];
    const float* Whh1 = (const float*)d_in[12];
    const float* bi1  = (const float*)d_in[13];
    const float* bh1  = (const float*)d_in[14];
    const float* Wo1  = (const float*)d_in[15];
    const float* bo1  = (const float*)d_in[16];
    const float* Wo2  = (const float*)d_in[17];
    const float* bo2  = (const float*)d_in[18];
    const float* Wg1  = (const float*)d_in[19];
    const float* bg1  = (const float*)d_in[20];
    const float* Wg2  = (const float*)d_in[21];
    const float* bg2  = (const float*)d_in[22];
    float* out = (float*)d_out;

    char* ws = (char*)d_ws;
    size_t off = 0;
    auto take = [&](size_t bytes) -> char* {
        char* pp = ws + off;
        off += (bytes + 255) & ~(size_t)255;
        return pp;
    };
    bf16* Wt0    = (bf16*)take(2048ull * 512 * 2);
    bf16* Wt1    = (bf16*)take(2048ull * 1024 * 2);
    bf16* Wo1t   = (bf16*)take(32ull * 512 * 2);
    bf16* Wg1t   = (bf16*)take(32ull * 512 * 2);
    bf16* Wit    = (bf16*)take(4096ull * 256 * 2);
    bf16* efb    = (bf16*)take((size_t)Bsz * Dsz * 2);
    bf16* ctxb   = (bf16*)take((size_t)Bsz * Dsz * 2);
    bf16* h0x    = (bf16*)take((size_t)Bsz * Hsz * 2);
    bf16* h0y    = (bf16*)take((size_t)Bsz * Hsz * 2);
    bf16* h1x    = (bf16*)take((size_t)Bsz * Hsz * 2);
    bf16* h1y    = (bf16*)take((size_t)Bsz * Hsz * 2);
    float* c0    = (float*)take((size_t)Bsz * Hsz * 4);
    float* c1    = (float*)take((size_t)Bsz * Hsz * 4);
    bf16* ctxg   = (bf16*)take((size_t)Bsz * 2048 * 2);
    (void)ws_size; (void)in_sizes; (void)n_in; (void)out_size;

    k_conv<<<2048, 256, 0, stream>>>(ef, ctx, Whi, Wci, Wih0, Whh0, Wih1, Whh1, Wo1, Wg1,
                                     efb, ctxb, Wit, Wt0, Wt1, Wo1t, Wg1t);
    k_init<<<dim3(32, 64), 256, 0, stream>>>(efb, ctxb, Wit, bh, bc, bi0, bh0,
                                             h0x, h1x, c0, c1, ctxg);

    for (int s = 0; s < Tsz; ++s) {
        int p = s & 1;
        const bf16* h0in  = p ? h0y : h0x;
        bf16*       h0out = p ? h0x : h0y;
        const bf16* h1in  = p ? h1y : h1x;
        bf16*       h1out = p ? h1x : h1y;
        k_gates<1><<<dim3(16, 32), 256, 0, stream>>>(
            h0in, nullptr, Wt0, ctxg, ii, h1in, Wih0, nullptr, nullptr,
            Wo1t, bo1, Wo2, bo2, c0, h0out, out, s);
        k_gates<0><<<dim3(16, 32), 256, 0, stream>>>(
            h0out, h1in, Wt1, nullptr, nullptr, nullptr, nullptr, bi1, bh1,
            nullptr, nullptr, nullptr, nullptr, c1, h1out, nullptr, s);
    }
    // s=44 wrote h1y; remaining outputs: step col 44 + global head
    k_intent<<<32, 256, 0, stream>>>(h1y, Wo1t, bo1, Wo2, bo2, out + 44, Tsz);
    k_intent<<<32, 256, 0, stream>>>(h1y, Wg1t, bg1, Wg2, bg2, out + (size_t)Bsz * Tsz, 1);
}